// Round 13
// baseline (370.174 us; speedup 1.0000x reference)
//
#include <hip/hip_runtime.h>

#define SEQL 2048
#define DMODEL 1024
#define HDIM 8192  // H*D

typedef unsigned short bf16_t;
typedef __attribute__((ext_vector_type(8))) short bf16x8;
typedef __attribute__((ext_vector_type(4))) float f32x4;

__device__ __forceinline__ bf16_t f2bf(float f) {
  unsigned u = __float_as_uint(f);
  u += 0x7fffu + ((u >> 16) & 1u);  // RNE
  return (bf16_t)(u >> 16);
}
__device__ __forceinline__ float bf2f(bf16_t b) {
  return __uint_as_float(((unsigned)b) << 16);
}

// ---------------- elementwise f32 -> bf16 ----------------
__global__ __launch_bounds__(256) void cvt_f32_bf16(const float* __restrict__ in,
                                                    bf16_t* __restrict__ out, int n) {
  int i = (blockIdx.x * 256 + threadIdx.x) * 4;
  if (i >= n) return;
  float4 f = *reinterpret_cast<const float4*>(in + i);
  ushort4 u;
  u.x = f2bf(f.x); u.y = f2bf(f.y); u.z = f2bf(f.z); u.w = f2bf(f.w);
  *reinterpret_cast<ushort4*>(out + i) = u;
}

// three f32 weight matrices (8192x1024 each) -> one concatenated bf16 buffer
__global__ __launch_bounds__(256) void cvt3_f32_bf16(const float* __restrict__ a,
                                                     const float* __restrict__ b,
                                                     const float* __restrict__ c,
                                                     bf16_t* __restrict__ out) {
  const int SEG = HDIM * DMODEL;  // 8388608
  int i = (blockIdx.x * 256 + threadIdx.x) * 4;
  const float* src;
  int off;
  if (i < SEG) { src = a; off = i; }
  else if (i < 2 * SEG) { src = b; off = i - SEG; }
  else { src = c; off = i - 2 * SEG; }
  float4 f = *reinterpret_cast<const float4*>(src + off);
  ushort4 u;
  u.x = f2bf(f.x); u.y = f2bf(f.y); u.z = f2bf(f.z); u.w = f2bf(f.w);
  *reinterpret_cast<ushort4*>(out + i) = u;
}

// concat bq,bk,bv (8192 each) -> 24576 f32
__global__ __launch_bounds__(256) void bias3(const float* __restrict__ a,
                                             const float* __restrict__ b,
                                             const float* __restrict__ c,
                                             float* __restrict__ out) {
  int i = blockIdx.x * 256 + threadIdx.x;
  float v = (i < HDIM) ? a[i] : (i < 2 * HDIM) ? b[i - HDIM] : c[i - 2 * HDIM];
  out[i] = v;
}

// tokens (DMODEL x SEQL) f32 -> tokensT (SEQL x DMODEL) bf16
__global__ __launch_bounds__(256) void transpose_cvt(const float* __restrict__ in,
                                                     bf16_t* __restrict__ out) {
  __shared__ float tile[32][33];
  int bx = blockIdx.x * 32;  // seq j
  int by = blockIdx.y * 32;  // channel c
  int tx = threadIdx.x, ty = threadIdx.y;
#pragma unroll
  for (int i = ty; i < 32; i += 8)
    tile[i][tx] = in[(size_t)(by + i) * SEQL + bx + tx];
  __syncthreads();
#pragma unroll
  for (int i = ty; i < 32; i += 8)
    out[(size_t)(bx + i) * DMODEL + by + tx] = f2bf(tile[tx][i]);
}

// softmax over the 8 heads (dim 0), in place on bf16 S[8][L*L]
__global__ __launch_bounds__(256) void softmax_heads(bf16_t* __restrict__ S) {
  const size_t HS = (size_t)SEQL * SEQL;
  size_t p = ((size_t)blockIdx.x * 256 + threadIdx.x) * 8;
  float v[8][8];
#pragma unroll
  for (int h = 0; h < 8; ++h) {
    bf16x8 x = *reinterpret_cast<const bf16x8*>(S + h * HS + p);
#pragma unroll
    for (int e = 0; e < 8; ++e) v[h][e] = bf2f((bf16_t)x[e]);
  }
#pragma unroll
  for (int e = 0; e < 8; ++e) {
    float mx = v[0][e];
#pragma unroll
    for (int h = 1; h < 8; ++h) mx = fmaxf(mx, v[h][e]);
    float s = 0.f;
#pragma unroll
    for (int h = 0; h < 8; ++h) { v[h][e] = __expf(v[h][e] - mx); s += v[h][e]; }
    float inv = 1.0f / s;
#pragma unroll
    for (int h = 0; h < 8; ++h) v[h][e] *= inv;
  }
#pragma unroll
  for (int h = 0; h < 8; ++h) {
    bf16x8 x;
#pragma unroll
    for (int e = 0; e < 8; ++e) x[e] = (short)f2bf(v[h][e]);
    *reinterpret_cast<bf16x8*>(S + h * HS + p) = x;
  }
}

// reduce 8 bf16 split-K partials P[z][D][L] -> out[D][L] f32 + bias[row]
__global__ __launch_bounds__(256) void reduce_out(const bf16_t* __restrict__ P,
                                                  const float* __restrict__ bo,
                                                  float* __restrict__ out) {
  const size_t NEL = (size_t)DMODEL * SEQL;
  size_t i = ((size_t)blockIdx.x * 256 + threadIdx.x) * 8;
  float s[8] = {0.f, 0.f, 0.f, 0.f, 0.f, 0.f, 0.f, 0.f};
#pragma unroll
  for (int z = 0; z < 8; ++z) {
    bf16x8 x = *reinterpret_cast<const bf16x8*>(P + z * NEL + i);
#pragma unroll
    for (int e = 0; e < 8; ++e) s[e] += bf2f((bf16_t)x[e]);
  }
  float bias = bo[i >> 11];  // row = i / SEQL
  float4 o0 = {s[0] + bias, s[1] + bias, s[2] + bias, s[3] + bias};
  float4 o1 = {s[4] + bias, s[5] + bias, s[6] + bias, s[7] + bias};
  *reinterpret_cast<float4*>(out + i) = o0;
  *reinterpret_cast<float4*>(out + i + 4) = o1;
}

// ---------------- C = scale * A·B^T (+bias[row]), 256x256 tile ----------------
// T3+T4 SCHEDULE (m201/m218: the only untried quadrant — 8-phase barriers
// WITH counted vmcnt). 512 thr = 8 waves (2M x 4N), BK=64.
// Per K-tile, 4 phases, each:
//   [stage] -> ds_read subtile -> s_barrier -> lgkmcnt(0) ->
//   setprio(1) 16 MFMA setprio(0) -> s_barrier        (8 barriers/tile)
// Read-liveness map (phases 0/2 read A rows 0-63/64-127; 1/3 read B only):
//   - B(t+1) staged phase 0 into bufB^1 (dead since last boundary).
//   - A(t+2) staged phase 3 IN-PLACE into bufA[t&1] — legal: A fully read
//     by end of phase 2, retired cross-wave by phase 2's trailing barrier.
// Boundary = s_waitcnt vmcnt(4): retires A(t+1)+B(t+1) (>=3 phases old,
// HBM latency covered) while A(t+2)'s 4 loads stay in flight — never
// drains to 0 in the main loop (T4). Tail tiles drain vmcnt(0).
// sched_barrier(0) after every barrier/wait pins stage/read motion
// (rule 18; raw s_barrier is not a compiler memory fence).
// LDS 128 KiB loop + 144 KiB arena for epilogues. 8-slot XOR swizzle both
// sides (rule #21). Z-flattened 1D grid + XCD-chunk swizzle (T1).
// Epilogues: EPI0 bf16 LDS-staged coalesced; EPI2 fused-QKV VSPLIT.
template <int EPI, bool HAS_BIAS>
__global__ __launch_bounds__(512, 2) void gemm256(
    const bf16_t* __restrict__ A, const bf16_t* __restrict__ B,
    bf16_t* __restrict__ C, bf16_t* __restrict__ C2, const float* __restrict__ bias,
    int K, int lda, int ldb, int ldc,
    long long sA, long long sB, long long sC, float scale, int gx, int gxy) {
  __shared__ alignas(16) char smem[147456];  // 144 KB arena
  auto* As = reinterpret_cast<bf16_t(*)[2][8192]>(smem);          // [2][half][128*64]
  auto* Bs = reinterpret_cast<bf16_t(*)[2][8192]>(smem + 65536);  // [2][half][128*64]
  const int nwg = gridDim.x;
  const int bid = blockIdx.x;
  const int swz = (nwg & 7) ? bid : ((bid & 7) * (nwg >> 3) + (bid >> 3));
  const int zz = swz / gxy;
  const int rem = swz - zz * gxy;
  const int brow = (rem / gx) * 256;
  const int bcol = (rem % gx) * 256;
  A += (long long)zz * sA;
  B += (long long)zz * sB;
  C += (long long)zz * sC;
  const int tid = threadIdx.x;
  const int w = tid >> 6, lane = tid & 63;
  const int fr = lane & 15, fq = lane >> 4;
  const int wr = w >> 2, wc = w & 3;

  int rj[2], cj[2];
#pragma unroll
  for (int j = 0; j < 2; ++j) {
    const int c = (w * 2 + j) * 64 + lane;
    rj[j] = c >> 3;
    cj[j] = ((c & 7) ^ (rj[j] & 7)) << 3;
  }

  auto stageA = [&](int buf, int kk) {  // both halves, 4 loads/thread
#pragma unroll
    for (int half = 0; half < 2; ++half)
#pragma unroll
      for (int j = 0; j < 2; ++j) {
        const bf16_t* g = A + (size_t)(brow + half * 128 + rj[j]) * lda + kk + cj[j];
        __builtin_amdgcn_global_load_lds(
            (const __attribute__((address_space(1))) void*)g,
            (__attribute__((address_space(3))) void*)(&As[buf][half][(w * 2 + j) * 512]),
            16, 0, 0);
      }
  };
  auto stageB = [&](int buf, int kk) {  // both halves, 4 loads/thread
#pragma unroll
    for (int half = 0; half < 2; ++half)
#pragma unroll
      for (int j = 0; j < 2; ++j) {
        const bf16_t* g = B + (size_t)(bcol + half * 128 + rj[j]) * ldb + kk + cj[j];
        __builtin_amdgcn_global_load_lds(
            (const __attribute__((address_space(1))) void*)g,
            (__attribute__((address_space(3))) void*)(&Bs[buf][half][(w * 2 + j) * 512]),
            16, 0, 0);
      }
  };

  auto ldA = [&](int buf, int mf, int kk) -> bf16x8 {
    const int rr = mf * 16 + fr;
    return *reinterpret_cast<const bf16x8*>(
        &As[buf][wr][rr * 64 + ((((kk << 2) | fq) ^ (rr & 7)) << 3)]);
  };
  auto ldB = [&](int buf, int nf, int kk) -> bf16x8 {
    const int rr = (wc & 1) * 64 + nf * 16 + fr;
    return *reinterpret_cast<const bf16x8*>(
        &Bs[buf][wc >> 1][rr * 64 + ((((kk << 2) | fq) ^ (rr & 7)) << 3)]);
  };

#define PHASE_SYNC()                                   \
  __builtin_amdgcn_s_barrier();                        \
  __builtin_amdgcn_sched_barrier(0);                   \
  asm volatile("s_waitcnt lgkmcnt(0)" ::: "memory");   \
  __builtin_amdgcn_sched_barrier(0)

#define PHASE_END()                                    \
  __builtin_amdgcn_s_barrier();                        \
  __builtin_amdgcn_sched_barrier(0)

  f32x4 acc[8][4];
  const f32x4 fzero = {0.f, 0.f, 0.f, 0.f};
#pragma unroll
  for (int m = 0; m < 8; ++m)
#pragma unroll
    for (int n = 0; n < 4; ++n) acc[m][n] = fzero;

  const int NT = K >> 6;  // K % 64 == 0, NT >= 3 at all call sites

  // prologue: A(0)->bufA0, B(0)->bufB0, A(1)->bufA1; retire A0+B0,
  // keep A(1)'s 4 loads in flight.
  stageA(0, 0);
  stageB(0, 0);
  stageA(1, 64);
  asm volatile("s_waitcnt vmcnt(4)" ::: "memory");
  __builtin_amdgcn_sched_barrier(0);
  __builtin_amdgcn_s_barrier();
  __builtin_amdgcn_sched_barrier(0);

  for (int t = 0; t < NT; ++t) {
    const int p = t & 1, q = p ^ 1;
    const bool pre1 = (t + 1 < NT), pre2 = (t + 2 < NT);
    bf16x8 af[4][2], bg[4][2];

    // ---- phase 0: acc[0-3][0-1] ----  (stage B(t+1) -> bufB q)
    if (pre1) stageB(q, (t + 1) << 6);
#pragma unroll
    for (int mf = 0; mf < 4; ++mf)
#pragma unroll
      for (int kk = 0; kk < 2; ++kk) af[mf][kk] = ldA(p, mf, kk);
#pragma unroll
    for (int nf = 0; nf < 2; ++nf)
#pragma unroll
      for (int kk = 0; kk < 2; ++kk) bg[nf][kk] = ldB(p, nf, kk);
    PHASE_SYNC();
    __builtin_amdgcn_s_setprio(1);
#pragma unroll
    for (int mf = 0; mf < 4; ++mf)
#pragma unroll
      for (int nf = 0; nf < 2; ++nf)
#pragma unroll
        for (int kk = 0; kk < 2; ++kk)
          acc[mf][nf] = __builtin_amdgcn_mfma_f32_16x16x32_bf16(
              af[mf][kk], bg[nf][kk], acc[mf][nf], 0, 0, 0);
    __builtin_amdgcn_s_setprio(0);
    PHASE_END();

    // ---- phase 1: acc[0-3][2-3] ----
#pragma unroll
    for (int nf = 2; nf < 4; ++nf)
#pragma unroll
      for (int kk = 0; kk < 2; ++kk) bg[nf][kk] = ldB(p, nf, kk);
    PHASE_SYNC();
    __builtin_amdgcn_s_setprio(1);
#pragma unroll
    for (int mf = 0; mf < 4; ++mf)
#pragma unroll
      for (int nf = 2; nf < 4; ++nf)
#pragma unroll
        for (int kk = 0; kk < 2; ++kk)
          acc[mf][nf] = __builtin_amdgcn_mfma_f32_16x16x32_bf16(
              af[mf][kk], bg[nf][kk], acc[mf][nf], 0, 0, 0);
    __builtin_amdgcn_s_setprio(0);
    PHASE_END();

    // ---- phase 2: acc[4-7][2-3] ----  (last A reads of this tile)
#pragma unroll
    for (int mf = 0; mf < 4; ++mf)
#pragma unroll
      for (int kk = 0; kk < 2; ++kk) af[mf][kk] = ldA(p, mf + 4, kk);
    PHASE_SYNC();
    __builtin_amdgcn_s_setprio(1);
#pragma unroll
    for (int mf = 0; mf < 4; ++mf)
#pragma unroll
      for (int nf = 2; nf < 4; ++nf)
#pragma unroll
        for (int kk = 0; kk < 2; ++kk)
          acc[mf + 4][nf] = __builtin_amdgcn_mfma_f32_16x16x32_bf16(
              af[mf][kk], bg[nf][kk], acc[mf + 4][nf], 0, 0, 0);
    __builtin_amdgcn_s_setprio(0);
    PHASE_END();

    // ---- phase 3: acc[4-7][0-1] ----  (stage A(t+2) IN-PLACE -> bufA p;
    // legal: all A(p) reads retired at phase 2's trailing barrier)
    if (pre2) stageA(p, (t + 2) << 6);
#pragma unroll
    for (int nf = 0; nf < 2; ++nf)
#pragma unroll
      for (int kk = 0; kk < 2; ++kk) bg[nf][kk] = ldB(p, nf, kk);
    PHASE_SYNC();
    __builtin_amdgcn_s_setprio(1);
#pragma unroll
    for (int mf = 0; mf < 4; ++mf)
#pragma unroll
      for (int nf = 0; nf < 2; ++nf)
#pragma unroll
        for (int kk = 0; kk < 2; ++kk)
          acc[mf + 4][nf] = __builtin_amdgcn_mfma_f32_16x16x32_bf16(
              af[mf][kk], bg[nf][kk], acc[mf + 4][nf], 0, 0, 0);
    __builtin_amdgcn_s_setprio(0);

    // boundary: retire A(t+1)+B(t+1) (>=3 phases old), keep A(t+2) flying.
    if (pre1) {
      __builtin_amdgcn_sched_barrier(0);
      if (pre2) {
        asm volatile("s_waitcnt vmcnt(4)" ::: "memory");
      } else {
        asm volatile("s_waitcnt vmcnt(0)" ::: "memory");
      }
      __builtin_amdgcn_sched_barrier(0);
      __builtin_amdgcn_s_barrier();
      __builtin_amdgcn_sched_barrier(0);
    }
  }
#undef PHASE_SYNC
#undef PHASE_END

  // ======== epilogues (LDS C-staging, coalesced stores) ========
  __syncthreads();  // all waves' LDS reads retired -> arena reusable

  const bool vseg = (EPI == 2) && (brow >= 2 * HDIM);
  if ((EPI == 0) || ((EPI == 2) && !vseg)) {  // bf16 C, [256][264] staging
    bf16_t* Ct = (bf16_t*)smem;
#pragma unroll
    for (int mf = 0; mf < 8; ++mf)
#pragma unroll
      for (int j = 0; j < 4; ++j) {
        const int orow = wr * 128 + mf * 16 + fq * 4 + j;
        float bvv = HAS_BIAS ? bias[brow + orow] : 0.f;
#pragma unroll
        for (int nf = 0; nf < 4; ++nf)
          Ct[orow * 264 + wc * 64 + nf * 16 + fr] = f2bf(acc[mf][nf][j] * scale + bvv);
      }
    __syncthreads();
#pragma unroll
    for (int i = 0; i < 16; ++i) {
      const int c = tid + i * 512;        // 16B chunk id, 8192 total
      const int row = c >> 5, ch = c & 31;
      *reinterpret_cast<bf16x8*>(&C[(size_t)(brow + row) * ldc + bcol + ch * 8]) =
          *reinterpret_cast<const bf16x8*>(smem + row * 528 + ch * 16);
    }
  } else if constexpr (EPI == 2) {  // V rows -> Vs[8][1024][2048] via C2
    const int vrow = brow - 2 * HDIM;
    bf16_t* Vt = (bf16_t*)smem;  // [4][256][72]: (h2, dloc, mloc)
#pragma unroll
    for (int mf = 0; mf < 8; ++mf)
#pragma unroll
      for (int j = 0; j < 4; ++j) {
        const int i = wr * 128 + mf * 16 + fq * 4 + j;  // local row; h2 = i&3 = j
        const int mloc = i >> 2;
        float bvv = HAS_BIAS ? bias[brow + i] : 0.f;
#pragma unroll
        for (int nf = 0; nf < 4; ++nf) {
          const int dloc = wc * 64 + nf * 16 + fr;
          Vt[(j * 256 + dloc) * 72 + mloc] = f2bf(acc[mf][nf][j] * scale + bvv);
        }
      }
    __syncthreads();
    const int r_ = bcol >> 10, d0 = bcol & 1023, m0 = vrow >> 2;
#pragma unroll
    for (int sIt = 0; sIt < 2; ++sIt) {
      const int s = tid + sIt * 512;      // seg id: 4 h2 x 256 dloc
      const int h2 = s >> 8, dloc = s & 255;
      const bf16_t* src = Vt + (h2 * 256 + dloc) * 72;
      bf16_t* dst = C2 + ((size_t)(2 * h2 + r_) * DMODEL + d0 + dloc) * SEQL + m0;
#pragma unroll
      for (int qq = 0; qq < 8; ++qq)
        *reinterpret_cast<bf16x8*>(dst + qq * 8) =
            *reinterpret_cast<const bf16x8*>(src + qq * 8);
    }
  }
}

extern "C" void kernel_launch(void* const* d_in, const int* in_sizes, int n_in,
                              void* d_out, int out_size, void* d_ws, size_t ws_size,
                              hipStream_t stream) {
  const float* tokens = (const float*)d_in[0];
  const float* Wq = (const float*)d_in[1];
  const float* bq = (const float*)d_in[2];
  const float* Wk = (const float*)d_in[3];
  const float* bk = (const float*)d_in[4];
  const float* Wv = (const float*)d_in[5];
  const float* bv = (const float*)d_in[6];
  const float* Wo = (const float*)d_in[7];
  const float* bo = (const float*)d_in[8];
  float* out = (float*)d_out;
  char* ws = (char*)d_ws;
  const size_t MB = 1024ull * 1024ull;
  // workspace layout (peak 176 MB):
  bf16_t* Vs = (bf16_t*)(ws + 0);          // Vsplit 32 MB [0,32)
  bf16_t* QmKm = (bf16_t*)(ws + 32 * MB);  // Qm||Km 64 MB [32,96)
  bf16_t* Qm = QmKm;                       // rows [0,8192)
  bf16_t* Km = QmKm + (size_t)HDIM * SEQL; // rows [8192,16384)
  bf16_t* Sb = (bf16_t*)(ws + 96 * MB);    // scores/attn 64 MB [96,160)
  bf16_t* tT = (bf16_t*)(ws + 96 * MB);    // tokensT 4 MB [96,100) (dead before Sb)
  bf16_t* Wqkv = (bf16_t*)(ws + 100 * MB); // 48 MB [100,148) (dead before Sb)
  float* bqkv = (float*)(ws + 148 * MB);   // 96 KB (dead before Sb)
  bf16_t* Wob = (bf16_t*)(ws + 160 * MB);  // Wo bf16 16 MB [160,176) (live all run)
  bf16_t* cT = (bf16_t*)(ws + 32 * MB);    // ctxT 32 MB (reuse Qm after scores)
  bf16_t* Pp = (bf16_t*)(ws + 96 * MB);    // bf16 split-K partials 32 MB (reuse Sb)

  dim3 b256(256);
  dim3 b512(512);
  const int nW = HDIM * DMODEL;  // 8388608

  // prep: tokensT, concatenated bf16 weights, concatenated bias, Wo bf16
  transpose_cvt<<<dim3(SEQL / 32, DMODEL / 32), dim3(32, 8), 0, stream>>>(tokens, tT);
  cvt3_f32_bf16<<<3 * nW / 1024, b256, 0, stream>>>(Wq, Wk, Wv, Wqkv);
  bias3<<<3 * HDIM / 256, b256, 0, stream>>>(bq, bk, bv, bqkv);
  cvt_f32_bf16<<<nW / 1024, b256, 0, stream>>>(Wo, Wob, nW);  // hoisted

  // fused QKV projection: M=24576, N=2048, K=1024; Q/K rows -> QmKm,
  // V rows -> Vs (VSPLIT). grid 96x8 = 768 blocks, 1D, XCD-chunked.
  gemm256<2, true><<<dim3(768, 1, 1), b512, 0, stream>>>(
      Wqkv, tT, QmKm, Vs, bqkv, DMODEL, DMODEL, DMODEL, SEQL,
      0, 0, 0, 1.0f, 8, 768);

  // scores[h][l,m] = (1/32) dot(Qm[l*8192+h*1024+:], Km[m*8192+h*1024+:])
  // z folded head-major: grid 8z*8y*8x = 512; each XCD owns one head.
  gemm256<0, false><<<dim3(512, 1, 1), b512, 0, stream>>>(
      Qm, Km, Sb, nullptr, nullptr, DMODEL, HDIM, HDIM, SEQL,
      1024, 1024, (long long)SEQL * SEQL, 0.03125f, 8, 64);

  // softmax over heads (dim 0), in place
  softmax_heads<<<(SEQL * SEQL / 8) / 256, b256, 0, stream>>>(Sb);

  // ctxT[l, h*1024+d] = sum_m attn[h][l,m] * Vs[h][d,m]; grid 8z*8y*4x = 256.
  gemm256<0, false><<<dim3(256, 1, 1), b512, 0, stream>>>(
      Sb, Vs, cT, nullptr, nullptr, SEQL, SEQL, SEQL, HDIM,
      (long long)SEQL * SEQL, (long long)DMODEL * SEQL, 1024, 1.0f, 4, 32);

  // out partials (bf16) = Wo_bf16 · ctxT^T, split-K=8 over K=8192;
  // grid 8z*4y*8x = 256. Bias applied in reduce_out.
  gemm256<0, false><<<dim3(256, 1, 1), b512, 0, stream>>>(
      Wob, cT, Pp, nullptr, nullptr, 1024, HDIM, HDIM, SEQL,
      1024, 1024, (long long)DMODEL * SEQL, 1.0f, 8, 32);
  reduce_out<<<(DMODEL * SEQL / 8) / 256, b256, 0, stream>>>(Pp, bo, out);
}

// Round 14
// 355.574 us; speedup vs baseline: 1.0411x; 1.0411x over previous
//
#include <hip/hip_runtime.h>

#define SEQL 2048
#define DMODEL 1024
#define HDIM 8192  // H*D

typedef unsigned short bf16_t;
typedef __attribute__((ext_vector_type(8))) short bf16x8;
typedef __attribute__((ext_vector_type(4))) float f32x4;

__device__ __forceinline__ bf16_t f2bf(float f) {
  unsigned u = __float_as_uint(f);
  u += 0x7fffu + ((u >> 16) & 1u);  // RNE
  return (bf16_t)(u >> 16);
}
__device__ __forceinline__ float bf2f(bf16_t b) {
  return __uint_as_float(((unsigned)b) << 16);
}

// four f32 weight matrices (8192x1024 each) -> Wqkv (3 concatenated) + Wob
__global__ __launch_bounds__(256) void cvt4_f32_bf16(const float* __restrict__ a,
                                                     const float* __restrict__ b,
                                                     const float* __restrict__ c,
                                                     const float* __restrict__ d,
                                                     bf16_t* __restrict__ out3,
                                                     bf16_t* __restrict__ outd) {
  const int SEG = HDIM * DMODEL;  // 8388608
  int i = (blockIdx.x * 256 + threadIdx.x) * 4;
  const float* src;
  bf16_t* dst;
  int off, oo;
  if (i < SEG) { src = a; dst = out3; off = i; oo = i; }
  else if (i < 2 * SEG) { src = b; dst = out3; off = i - SEG; oo = i; }
  else if (i < 3 * SEG) { src = c; dst = out3; off = i - 2 * SEG; oo = i; }
  else { src = d; dst = outd; off = i - 3 * SEG; oo = i - 3 * SEG; }
  float4 f = *reinterpret_cast<const float4*>(src + off);
  ushort4 u;
  u.x = f2bf(f.x); u.y = f2bf(f.y); u.z = f2bf(f.z); u.w = f2bf(f.w);
  *reinterpret_cast<ushort4*>(dst + oo) = u;
}

// concat bq,bk,bv (8192 each) -> 24576 f32
__global__ __launch_bounds__(256) void bias3(const float* __restrict__ a,
                                             const float* __restrict__ b,
                                             const float* __restrict__ c,
                                             float* __restrict__ out) {
  int i = blockIdx.x * 256 + threadIdx.x;
  float v = (i < HDIM) ? a[i] : (i < 2 * HDIM) ? b[i - HDIM] : c[i - 2 * HDIM];
  out[i] = v;
}

// tokens (DMODEL x SEQL) f32 -> tokensT (SEQL x DMODEL) bf16
__global__ __launch_bounds__(256) void transpose_cvt(const float* __restrict__ in,
                                                     bf16_t* __restrict__ out) {
  __shared__ float tile[32][33];
  int bx = blockIdx.x * 32;  // seq j
  int by = blockIdx.y * 32;  // channel c
  int tx = threadIdx.x, ty = threadIdx.y;
#pragma unroll
  for (int i = ty; i < 32; i += 8)
    tile[i][tx] = in[(size_t)(by + i) * SEQL + bx + tx];
  __syncthreads();
#pragma unroll
  for (int i = ty; i < 32; i += 8)
    out[(size_t)(bx + i) * DMODEL + by + tx] = f2bf(tile[tx][i]);
}

// softmax over the 8 heads (dim 0), in place on bf16 S[8][L*L]
__global__ __launch_bounds__(256) void softmax_heads(bf16_t* __restrict__ S) {
  const size_t HS = (size_t)SEQL * SEQL;
  size_t p = ((size_t)blockIdx.x * 256 + threadIdx.x) * 8;
  float v[8][8];
#pragma unroll
  for (int h = 0; h < 8; ++h) {
    bf16x8 x = *reinterpret_cast<const bf16x8*>(S + h * HS + p);
#pragma unroll
    for (int e = 0; e < 8; ++e) v[h][e] = bf2f((bf16_t)x[e]);
  }
#pragma unroll
  for (int e = 0; e < 8; ++e) {
    float mx = v[0][e];
#pragma unroll
    for (int h = 1; h < 8; ++h) mx = fmaxf(mx, v[h][e]);
    float s = 0.f;
#pragma unroll
    for (int h = 0; h < 8; ++h) { v[h][e] = __expf(v[h][e] - mx); s += v[h][e]; }
    float inv = 1.0f / s;
#pragma unroll
    for (int h = 0; h < 8; ++h) v[h][e] *= inv;
  }
#pragma unroll
  for (int h = 0; h < 8; ++h) {
    bf16x8 x;
#pragma unroll
    for (int e = 0; e < 8; ++e) x[e] = (short)f2bf(v[h][e]);
    *reinterpret_cast<bf16x8*>(S + h * HS + p) = x;
  }
}

// reduce 8 bf16 split-K partials P[z][D][L] -> out[D][L] f32 + bias[row]
__global__ __launch_bounds__(256) void reduce_out(const bf16_t* __restrict__ P,
                                                  const float* __restrict__ bo,
                                                  float* __restrict__ out) {
  const size_t NEL = (size_t)DMODEL * SEQL;
  size_t i = ((size_t)blockIdx.x * 256 + threadIdx.x) * 8;
  float s[8] = {0.f, 0.f, 0.f, 0.f, 0.f, 0.f, 0.f, 0.f};
#pragma unroll
  for (int z = 0; z < 8; ++z) {
    bf16x8 x = *reinterpret_cast<const bf16x8*>(P + z * NEL + i);
#pragma unroll
    for (int e = 0; e < 8; ++e) s[e] += bf2f((bf16_t)x[e]);
  }
  float bias = bo[i >> 11];  // row = i / SEQL
  float4 o0 = {s[0] + bias, s[1] + bias, s[2] + bias, s[3] + bias};
  float4 o1 = {s[4] + bias, s[5] + bias, s[6] + bias, s[7] + bias};
  *reinterpret_cast<float4*>(out + i) = o0;
  *reinterpret_cast<float4*>(out + i + 4) = o1;
}

// ---------------- C = scale * A·B^T (+bias[row]), 256x256 tile ----------------
// R5/R8/R11 core — MEASURED BEST (four lockstep/counted schedule variants
// R6/R7/R12/R13 all regressed vs this free-run body): 512 thr = 8 waves
// (2M x 4N), BK=64, double-buffered LDS, 4 free-run MFMA groups per K-tile,
// stages issued in groups 0-1, ONE __syncthreads per tile boundary.
// 8-slot XOR swizzle both sides (rule #21) -> conflict-free ds_read_b128.
// Z-FLATTENED 1D GRID with XCD-chunk swizzle (T1): z = swz/gxy -> each XCD
// owns one z (head / K-slice) -> L2-local panels.
// Epilogues (LDS C-staging, coalesced):
//   EPI 0 (bf16): acc -> LDS [256][264] -> b128 -> 16B stores.
//   EPI 2 (fused QKV): rows < 16384 -> EPI0 into C (Qm||Km contiguous);
//     rows >= 16384 -> VSPLIT into C2 = Vs[h][d][m]:
//     g=vrow+i, tok=bcol+dloc; m=g>>2, h2=(g&3)=j, r=tok>>10, d=tok&1023.
template <int EPI, bool HAS_BIAS>
__global__ __launch_bounds__(512, 2) void gemm256(
    const bf16_t* __restrict__ A, const bf16_t* __restrict__ B,
    bf16_t* __restrict__ C, bf16_t* __restrict__ C2, const float* __restrict__ bias,
    int K, int lda, int ldb, int ldc,
    long long sA, long long sB, long long sC, float scale, int gx, int gxy) {
  __shared__ alignas(16) char smem[147456];  // 144 KB arena
  auto* As = reinterpret_cast<bf16_t(*)[2][8192]>(smem);  // [buf][half][128*64]
  auto* Bs = reinterpret_cast<bf16_t(*)[2][8192]>(smem + 65536);
  const int nwg = gridDim.x;
  const int bid = blockIdx.x;
  const int swz = (nwg & 7) ? bid : ((bid & 7) * (nwg >> 3) + (bid >> 3));
  const int zz = swz / gxy;
  const int rem = swz - zz * gxy;
  const int brow = (rem / gx) * 256;
  const int bcol = (rem % gx) * 256;
  A += (long long)zz * sA;
  B += (long long)zz * sB;
  C += (long long)zz * sC;
  const int tid = threadIdx.x;
  const int w = tid >> 6, lane = tid & 63;
  const int fr = lane & 15, fq = lane >> 4;
  const int wr = w >> 2, wc = w & 3;

  int rj[2], cj[2];
#pragma unroll
  for (int j = 0; j < 2; ++j) {
    const int c = (w * 2 + j) * 64 + lane;
    rj[j] = c >> 3;
    cj[j] = ((c & 7) ^ (rj[j] & 7)) << 3;
  }

  auto stageA = [&](int buf, int half, int kk) {
#pragma unroll
    for (int j = 0; j < 2; ++j) {
      const bf16_t* g = A + (size_t)(brow + half * 128 + rj[j]) * lda + kk + cj[j];
      __builtin_amdgcn_global_load_lds(
          (const __attribute__((address_space(1))) void*)g,
          (__attribute__((address_space(3))) void*)(&As[buf][half][(w * 2 + j) * 512]),
          16, 0, 0);
    }
  };
  auto stageB = [&](int buf, int half, int kk) {
#pragma unroll
    for (int j = 0; j < 2; ++j) {
      const bf16_t* g = B + (size_t)(bcol + half * 128 + rj[j]) * ldb + kk + cj[j];
      __builtin_amdgcn_global_load_lds(
          (const __attribute__((address_space(1))) void*)g,
          (__attribute__((address_space(3))) void*)(&Bs[buf][half][(w * 2 + j) * 512]),
          16, 0, 0);
    }
  };

  auto ldA = [&](int buf, int mf, int kk) -> bf16x8 {
    const int rr = mf * 16 + fr;
    return *reinterpret_cast<const bf16x8*>(
        &As[buf][wr][rr * 64 + ((((kk << 2) | fq) ^ (rr & 7)) << 3)]);
  };
  auto ldB = [&](int buf, int nf, int kk) -> bf16x8 {
    const int rr = (wc & 1) * 64 + nf * 16 + fr;
    return *reinterpret_cast<const bf16x8*>(
        &Bs[buf][wc >> 1][rr * 64 + ((((kk << 2) | fq) ^ (rr & 7)) << 3)]);
  };

  f32x4 acc[8][4];
  const f32x4 fzero = {0.f, 0.f, 0.f, 0.f};
#pragma unroll
  for (int m = 0; m < 8; ++m)
#pragma unroll
    for (int n = 0; n < 4; ++n) acc[m][n] = fzero;

  const int NT = K >> 6;  // K % 64 == 0, NT >= 2 at all call sites
  stageA(0, 0, 0); stageA(0, 1, 0); stageB(0, 0, 0); stageB(0, 1, 0);
  __syncthreads();

  for (int t = 0; t < NT; ++t) {
    const int p = t & 1, q = p ^ 1;
    const int kn = (t + 1) << 6;
    const bool pre = (t + 1 < NT);
    bf16x8 af[4][2], bg[4][2];

    // ---- group 0: rows 0-63 x cols 0-31 ----
    if (pre) { stageA(q, 0, kn); stageA(q, 1, kn); }
#pragma unroll
    for (int mf = 0; mf < 4; ++mf)
#pragma unroll
      for (int kk = 0; kk < 2; ++kk) af[mf][kk] = ldA(p, mf, kk);
#pragma unroll
    for (int nf = 0; nf < 2; ++nf)
#pragma unroll
      for (int kk = 0; kk < 2; ++kk) bg[nf][kk] = ldB(p, nf, kk);
    __builtin_amdgcn_s_setprio(1);
#pragma unroll
    for (int mf = 0; mf < 4; ++mf)
#pragma unroll
      for (int nf = 0; nf < 2; ++nf)
#pragma unroll
        for (int kk = 0; kk < 2; ++kk)
          acc[mf][nf] = __builtin_amdgcn_mfma_f32_16x16x32_bf16(
              af[mf][kk], bg[nf][kk], acc[mf][nf], 0, 0, 0);
    __builtin_amdgcn_s_setprio(0);

    // ---- group 1: rows 0-63 x cols 32-63 ----
    if (pre) { stageB(q, 0, kn); stageB(q, 1, kn); }
#pragma unroll
    for (int nf = 2; nf < 4; ++nf)
#pragma unroll
      for (int kk = 0; kk < 2; ++kk) bg[nf][kk] = ldB(p, nf, kk);
    __builtin_amdgcn_s_setprio(1);
#pragma unroll
    for (int mf = 0; mf < 4; ++mf)
#pragma unroll
      for (int nf = 2; nf < 4; ++nf)
#pragma unroll
        for (int kk = 0; kk < 2; ++kk)
          acc[mf][nf] = __builtin_amdgcn_mfma_f32_16x16x32_bf16(
              af[mf][kk], bg[nf][kk], acc[mf][nf], 0, 0, 0);
    __builtin_amdgcn_s_setprio(0);

    // ---- group 2: rows 64-127 x cols 32-63 ----
#pragma unroll
    for (int mf = 0; mf < 4; ++mf)
#pragma unroll
      for (int kk = 0; kk < 2; ++kk) af[mf][kk] = ldA(p, mf + 4, kk);
    __builtin_amdgcn_s_setprio(1);
#pragma unroll
    for (int mf = 0; mf < 4; ++mf)
#pragma unroll
      for (int nf = 2; nf < 4; ++nf)
#pragma unroll
        for (int kk = 0; kk < 2; ++kk)
          acc[mf + 4][nf] = __builtin_amdgcn_mfma_f32_16x16x32_bf16(
              af[mf][kk], bg[nf][kk], acc[mf + 4][nf], 0, 0, 0);
    __builtin_amdgcn_s_setprio(0);

    // ---- group 3: rows 64-127 x cols 0-31 ----
#pragma unroll
    for (int nf = 0; nf < 2; ++nf)
#pragma unroll
      for (int kk = 0; kk < 2; ++kk) bg[nf][kk] = ldB(p, nf, kk);
    __builtin_amdgcn_s_setprio(1);
#pragma unroll
    for (int mf = 0; mf < 4; ++mf)
#pragma unroll
      for (int nf = 0; nf < 2; ++nf)
#pragma unroll
        for (int kk = 0; kk < 2; ++kk)
          acc[mf + 4][nf] = __builtin_amdgcn_mfma_f32_16x16x32_bf16(
              af[mf][kk], bg[nf][kk], acc[mf + 4][nf], 0, 0, 0);
    __builtin_amdgcn_s_setprio(0);

    if (pre) __syncthreads();
  }

  // ======== epilogues (LDS C-staging, coalesced stores) ========
  __syncthreads();  // all waves' LDS reads retired -> arena reusable

  const bool vseg = (EPI == 2) && (brow >= 2 * HDIM);
  if ((EPI == 0) || ((EPI == 2) && !vseg)) {  // bf16 C, [256][264] staging
    bf16_t* Ct = (bf16_t*)smem;
#pragma unroll
    for (int mf = 0; mf < 8; ++mf)
#pragma unroll
      for (int j = 0; j < 4; ++j) {
        const int orow = wr * 128 + mf * 16 + fq * 4 + j;
        float bvv = HAS_BIAS ? bias[brow + orow] : 0.f;
#pragma unroll
        for (int nf = 0; nf < 4; ++nf)
          Ct[orow * 264 + wc * 64 + nf * 16 + fr] = f2bf(acc[mf][nf][j] * scale + bvv);
      }
    __syncthreads();
#pragma unroll
    for (int i = 0; i < 16; ++i) {
      const int c = tid + i * 512;        // 16B chunk id, 8192 total
      const int row = c >> 5, ch = c & 31;
      *reinterpret_cast<bf16x8*>(&C[(size_t)(brow + row) * ldc + bcol + ch * 8]) =
          *reinterpret_cast<const bf16x8*>(smem + row * 528 + ch * 16);
    }
  } else if constexpr (EPI == 2) {  // V rows -> Vs[8][1024][2048] via C2
    const int vrow = brow - 2 * HDIM;
    bf16_t* Vt = (bf16_t*)smem;  // [4][256][72]: (h2, dloc, mloc)
#pragma unroll
    for (int mf = 0; mf < 8; ++mf)
#pragma unroll
      for (int j = 0; j < 4; ++j) {
        const int i = wr * 128 + mf * 16 + fq * 4 + j;  // local row; h2 = i&3 = j
        const int mloc = i >> 2;
        float bvv = HAS_BIAS ? bias[brow + i] : 0.f;
#pragma unroll
        for (int nf = 0; nf < 4; ++nf) {
          const int dloc = wc * 64 + nf * 16 + fr;
          Vt[(j * 256 + dloc) * 72 + mloc] = f2bf(acc[mf][nf][j] * scale + bvv);
        }
      }
    __syncthreads();
    const int r_ = bcol >> 10, d0 = bcol & 1023, m0 = vrow >> 2;
#pragma unroll
    for (int sIt = 0; sIt < 2; ++sIt) {
      const int s = tid + sIt * 512;      // seg id: 4 h2 x 256 dloc
      const int h2 = s >> 8, dloc = s & 255;
      const bf16_t* src = Vt + (h2 * 256 + dloc) * 72;
      bf16_t* dst = C2 + ((size_t)(2 * h2 + r_) * DMODEL + d0 + dloc) * SEQL + m0;
#pragma unroll
      for (int qq = 0; qq < 8; ++qq)
        *reinterpret_cast<bf16x8*>(dst + qq * 8) =
            *reinterpret_cast<const bf16x8*>(src + qq * 8);
    }
  }
}

extern "C" void kernel_launch(void* const* d_in, const int* in_sizes, int n_in,
                              void* d_out, int out_size, void* d_ws, size_t ws_size,
                              hipStream_t stream) {
  const float* tokens = (const float*)d_in[0];
  const float* Wq = (const float*)d_in[1];
  const float* bq = (const float*)d_in[2];
  const float* Wk = (const float*)d_in[3];
  const float* bk = (const float*)d_in[4];
  const float* Wv = (const float*)d_in[5];
  const float* bv = (const float*)d_in[6];
  const float* Wo = (const float*)d_in[7];
  const float* bo = (const float*)d_in[8];
  float* out = (float*)d_out;
  char* ws = (char*)d_ws;
  const size_t MB = 1024ull * 1024ull;
  // workspace layout (peak 176 MB):
  bf16_t* Vs = (bf16_t*)(ws + 0);          // Vsplit 32 MB [0,32)
  bf16_t* QmKm = (bf16_t*)(ws + 32 * MB);  // Qm||Km 64 MB [32,96)
  bf16_t* Qm = QmKm;                       // rows [0,8192)
  bf16_t* Km = QmKm + (size_t)HDIM * SEQL; // rows [8192,16384)
  bf16_t* Sb = (bf16_t*)(ws + 96 * MB);    // scores/attn 64 MB [96,160)
  bf16_t* tT = (bf16_t*)(ws + 96 * MB);    // tokensT 4 MB [96,100) (dead before Sb)
  bf16_t* Wqkv = (bf16_t*)(ws + 100 * MB); // 48 MB [100,148) (dead before Sb)
  float* bqkv = (float*)(ws + 148 * MB);   // 96 KB (dead before Sb)
  bf16_t* Wob = (bf16_t*)(ws + 160 * MB);  // Wo bf16 16 MB [160,176) (live all run)
  bf16_t* cT = (bf16_t*)(ws + 32 * MB);    // ctxT 32 MB (reuse Qm after scores)
  bf16_t* Pp = (bf16_t*)(ws + 96 * MB);    // bf16 split-K partials 32 MB (reuse Sb)

  dim3 b256(256);
  dim3 b512(512);
  const int nW = HDIM * DMODEL;  // 8388608

  // prep: tokensT, all four weights converted in one pass, concatenated bias
  transpose_cvt<<<dim3(SEQL / 32, DMODEL / 32), dim3(32, 8), 0, stream>>>(tokens, tT);
  cvt4_f32_bf16<<<4 * nW / 1024, b256, 0, stream>>>(Wq, Wk, Wv, Wo, Wqkv, Wob);
  bias3<<<3 * HDIM / 256, b256, 0, stream>>>(bq, bk, bv, bqkv);

  // fused QKV projection: M=24576, N=2048, K=1024; Q/K rows -> QmKm,
  // V rows -> Vs (VSPLIT). grid 96x8 = 768 blocks, 1D, XCD-chunked.
  gemm256<2, true><<<dim3(768, 1, 1), b512, 0, stream>>>(
      Wqkv, tT, QmKm, Vs, bqkv, DMODEL, DMODEL, DMODEL, SEQL,
      0, 0, 0, 1.0f, 8, 768);

  // scores[h][l,m] = (1/32) dot(Qm[l*8192+h*1024+:], Km[m*8192+h*1024+:])
  // z folded head-major: grid 8z*8y*8x = 512; each XCD owns one head.
  gemm256<0, false><<<dim3(512, 1, 1), b512, 0, stream>>>(
      Qm, Km, Sb, nullptr, nullptr, DMODEL, HDIM, HDIM, SEQL,
      1024, 1024, (long long)SEQL * SEQL, 0.03125f, 8, 64);

  // softmax over heads (dim 0), in place
  softmax_heads<<<(SEQL * SEQL / 8) / 256, b256, 0, stream>>>(Sb);

  // ctxT[l, h*1024+d] = sum_m attn[h][l,m] * Vs[h][d,m]; grid 8z*8y*4x = 256.
  gemm256<0, false><<<dim3(256, 1, 1), b512, 0, stream>>>(
      Sb, Vs, cT, nullptr, nullptr, SEQL, SEQL, SEQL, HDIM,
      (long long)SEQL * SEQL, (long long)DMODEL * SEQL, 1024, 1.0f, 4, 32);

  // out partials (bf16) = Wo_bf16 · ctxT^T, split-K=8 over K=8192;
  // grid 8z*4y*8x = 256. Bias applied in reduce_out.
  gemm256<0, false><<<dim3(256, 1, 1), b512, 0, stream>>>(
      Wob, cT, Pp, nullptr, nullptr, 1024, HDIM, HDIM, SEQL,
      1024, 1024, (long long)DMODEL * SEQL, 1.0f, 8, 32);
  reduce_out<<<(DMODEL * SEQL / 8) / 256, b256, 0, stream>>>(Pp, bo, out);
}